// Round 7
// baseline (685.462 us; speedup 1.0000x reference)
//
#include <hip/hip_runtime.h>
#include <stdint.h>
#include <stddef.h>

// ================= helpers =================
__device__ __forceinline__ float bl(unsigned u){ return __uint_as_float(u << 16); }
__device__ __forceinline__ float bh(unsigned u){ return __uint_as_float(u & 0xffff0000u); }
__device__ __forceinline__ float b2f(unsigned short v){ return __uint_as_float(((unsigned)v) << 16); }
__device__ __forceinline__ unsigned short f2bf(float f){
    unsigned u = __float_as_uint(f);
    unsigned r = (u + 0x7fffu + ((u >> 16) & 1u)) >> 16;
    return (unsigned short)r;
}
__device__ __forceinline__ uint2 ntload_u2(const uint2* p){
    unsigned long long v = __builtin_nontemporal_load((const unsigned long long*)p);
    uint2 r; r.x = (unsigned)v; r.y = (unsigned)(v >> 32); return r;
}
__device__ __forceinline__ void ntstore_u2(uint2* p, unsigned x, unsigned y){
    unsigned long long v = ((unsigned long long)y << 32) | (unsigned long long)x;
    __builtin_nontemporal_store(v, (unsigned long long*)p);
}

// ====== combined detection: mask dtype (bits 0,1) + label_init uniformity (bit 2) ======
__global__ void detect_kernel(const unsigned char* __restrict__ mp, int n,
                              const unsigned* __restrict__ li, long li_n,
                              unsigned* __restrict__ flags){
    long i = (long)blockIdx.x*blockDim.x + threadIdx.x;
    unsigned f = 0;
    if(i < n){
        unsigned char b = mp[i];
        if((i & 3) && b) f |= 1u;
        if(b == 0x3Fu)   f |= 2u;
    }
    if(i < li_n){
        if(li[i] != li[0]) f |= 4u;
    }
    if(f) atomicOr(flags, f);
}
__device__ __forceinline__ float get_mask(const void* p, unsigned flags, int i){
    if((flags & 1u) == 0) return ((const int*)p)[i] ? 1.0f : 0.0f;
    if(flags & 2u)        return ((const float*)p)[i];
    return ((const unsigned char*)p)[i] ? 1.0f : 0.0f;
}

// ================= small weight products: W0c=W0@Wcls, W1c=W1@Wcls, biases =================
__global__ void small_w_kernel(const float* __restrict__ W0, const float* __restrict__ b0,
                               const float* __restrict__ W1, const float* __restrict__ b1,
                               const float* __restrict__ Wcls, const float* __restrict__ bcls,
                               float* __restrict__ W0c, float* __restrict__ W1c,
                               float* __restrict__ b0c, float* __restrict__ b1c)
{
    int t = threadIdx.x;
    for(int i = t; i < 2048; i += 256){
        int d = i >> 4, c = i & 15;
        float s0 = 0.f, s1 = 0.f;
        for(int k = 0; k < 64; k++){
            float wc = Wcls[k*16 + c];
            s0 += W0[d*64 + k]*wc;
            s1 += W1[d*64 + k]*wc;
        }
        W0c[i] = s0; W1c[i] = s1;
    }
    if(t < 16){
        float s0 = 0.f, s1 = 0.f;
        for(int k = 0; k < 64; k++){
            float wc = Wcls[k*16 + t];
            s0 += b0[k]*wc; s1 += b1[k]*wc;
        }
        b0c[t] = s0 + bcls[t];
        b1c[t] = s1;
    }
}

// ====== fused projection: fph(bf16,N*64)=feats0@Wp ; h0c(f32,N*16)=feats0@W0c+b0c ======
__global__ __launch_bounds__(256) void proj_fused0(
    const float* __restrict__ X, const float* __restrict__ Wp,
    const float* __restrict__ W0c, const float* __restrict__ b0c,
    unsigned short* __restrict__ fph, float* __restrict__ h0c, int rows)
{
    __shared__ float Wl[128*64];    // 32 KB
    __shared__ float Wcl[128*16];   // 8 KB
    __shared__ float ftile[32*128]; // 16 KB
    int t = threadIdx.x;
    for(int i = t; i < 2048; i += 256) ((float4*)Wl)[i]  = ((const float4*)Wp)[i];
    for(int i = t; i < 512;  i += 256) ((float4*)Wcl)[i] = ((const float4*)W0c)[i];
    int c4 = (t & 15)*4;
    int col16 = t & 15;
    int r2 = (t >> 4)*2;
    float bc = b0c[col16];
    for(long base = (long)blockIdx.x*32; base < rows; base += (long)gridDim.x*32){
        int nr = min(32, (int)(rows - base));
        __syncthreads();
        for(int i = t; i < nr*32; i += 256){
            int r = i >> 5, q = i & 31;
            ((float4*)ftile)[r*32 + q] = ((const float4*)X)[(base + r)*32 + q];
        }
        __syncthreads();
        float a00=0,a01=0,a02=0,a03=0, a10=0,a11=0,a12=0,a13=0;
        float c0 = bc, c1 = bc;
        #pragma unroll 4
        for(int k = 0; k < 128; k++){
            float4 w = *((const float4*)(Wl + k*64 + c4));
            float wc = Wcl[k*16 + col16];
            float x0 = ftile[r2*128 + k];
            float x1 = ftile[(r2+1)*128 + k];
            a00 += x0*w.x; a01 += x0*w.y; a02 += x0*w.z; a03 += x0*w.w; c0 += x0*wc;
            a10 += x1*w.x; a11 += x1*w.y; a12 += x1*w.z; a13 += x1*w.w; c1 += x1*wc;
        }
        if(r2 < nr){
            ushort4 o; o.x=f2bf(a00); o.y=f2bf(a01); o.z=f2bf(a02); o.w=f2bf(a03);
            *((ushort4*)(fph + (base + r2)*64 + c4)) = o;
            h0c[(base + r2)*16 + col16] = c0;
        }
        if(r2 + 1 < nr){
            ushort4 o; o.x=f2bf(a10); o.y=f2bf(a11); o.z=f2bf(a12); o.w=f2bf(a13);
            *((ushort4*)(fph + (base + r2 + 1)*64 + c4)) = o;
            h0c[(base + r2 + 1)*16 + col16] = c1;
        }
    }
}

// ================= proj to C=16 (bf16 out): Y = X@Wc + bias =================
__global__ __launch_bounds__(256) void proj16_kernel(
    const float* __restrict__ X, const float* __restrict__ Wc,
    const float* __restrict__ biasc, unsigned short* __restrict__ Y, int rows)
{
    __shared__ float Wcl[128*16];   // 8 KB
    __shared__ float ftile[64*128]; // 32 KB
    int t = threadIdx.x;
    for(int i = t; i < 512; i += 256) ((float4*)Wcl)[i] = ((const float4*)Wc)[i];
    int col = t & 15;
    int r4 = (t >> 4)*4;
    float bc = biasc[col];
    for(long base = (long)blockIdx.x*64; base < rows; base += (long)gridDim.x*64){
        int nr = min(64, (int)(rows - base));
        __syncthreads();
        for(int i = t; i < nr*32; i += 256){
            int r = i >> 5, q = i & 31;
            ((float4*)ftile)[r*32 + q] = ((const float4*)X)[(base + r)*32 + q];
        }
        __syncthreads();
        float acc0 = bc, acc1 = bc, acc2 = bc, acc3 = bc;
        #pragma unroll 4
        for(int k = 0; k < 128; k++){
            float wc = Wcl[k*16 + col];
            acc0 += ftile[(r4+0)*128 + k]*wc;
            acc1 += ftile[(r4+1)*128 + k]*wc;
            acc2 += ftile[(r4+2)*128 + k]*wc;
            acc3 += ftile[(r4+3)*128 + k]*wc;
        }
        if(r4+0 < nr) Y[(base + r4 + 0)*16 + col] = f2bf(acc0);
        if(r4+1 < nr) Y[(base + r4 + 1)*16 + col] = f2bf(acc1);
        if(r4+2 < nr) Y[(base + r4 + 2)*16 + col] = f2bf(acc2);
        if(r4+3 < nr) Y[(base + r4 + 3)*16 + col] = f2bf(acc3);
    }
}

// ================= CSR build: degree count =================
__global__ __launch_bounds__(256) void count_kernel(
    const int* __restrict__ dst0, const int* __restrict__ dst1, const int* __restrict__ dst2,
    int* __restrict__ deg, int n, int eg)
{
    long tid = (long)blockIdx.x*blockDim.x + threadIdx.x;
    if(tid >= 3L*eg) return;
    int g = (int)(tid / eg);
    int e = (int)(tid - (long)g*eg);
    const int* dp = g==0 ? dst0 : (g==1 ? dst1 : dst2);
    int d = __builtin_nontemporal_load(dp + e);
    atomicAdd(&deg[(long)g*n + d], 1);
}

// ================= scan: blockwise inclusive (1024 elems/block) =================
__global__ __launch_bounds__(256) void scanA_kernel(const int* __restrict__ deg,
                                                    int* __restrict__ incl,
                                                    int* __restrict__ bsum, int n3)
{
    __shared__ int sh[256];
    int t = threadIdx.x;
    long base = (long)blockIdx.x*1024 + t*4;
    int v0=0,v1=0,v2=0,v3=0;
    if(base   < n3) v0 = deg[base];
    if(base+1 < n3) v1 = deg[base+1];
    if(base+2 < n3) v2 = deg[base+2];
    if(base+3 < n3) v3 = deg[base+3];
    int tot = v0+v1+v2+v3;
    sh[t] = tot;
    __syncthreads();
    for(int ofs = 1; ofs < 256; ofs <<= 1){
        int add = (t >= ofs) ? sh[t-ofs] : 0;
        __syncthreads();
        sh[t] += add;
        __syncthreads();
    }
    int pre = sh[t] - tot;
    if(t == 255) bsum[blockIdx.x] = sh[255];
    int s0 = pre+v0, s1 = s0+v1, s2 = s1+v2, s3 = s2+v3;
    if(base   < n3) incl[base]   = s0;
    if(base+1 < n3) incl[base+1] = s1;
    if(base+2 < n3) incl[base+2] = s2;
    if(base+3 < n3) incl[base+3] = s3;
}

__global__ __launch_bounds__(512) void scanB_kernel(int* __restrict__ bsum, int nb)
{
    __shared__ int sh[512];
    int t = threadIdx.x;
    int v = (t < nb) ? bsum[t] : 0;
    sh[t] = v;
    __syncthreads();
    for(int ofs = 1; ofs < 512; ofs <<= 1){
        int add = (t >= ofs) ? sh[t-ofs] : 0;
        __syncthreads();
        sh[t] += add;
        __syncthreads();
    }
    if(t < nb) bsum[t] = sh[t] - v;   // exclusive
}

__global__ __launch_bounds__(256) void scanC_kernel(const int* __restrict__ incl,
                                                    const int* __restrict__ boff,
                                                    int* __restrict__ rowptr,
                                                    int* __restrict__ cursor, int n3)
{
    int i = blockIdx.x*blockDim.x + threadIdx.x;
    if(i >= n3) return;
    int ex = (i == 0) ? 0 : (incl[i-1] + boff[(i-1) >> 10]);
    rowptr[i] = ex;
    cursor[i] = ex;
    if(i == n3-1) rowptr[n3] = incl[i] + boff[i >> 10];
}

// ====== FUSED scores + packed-record scatter, 4-edge ILP per 8-lane group ======
// 8 independent 128B gathers + 4 independent atomic chains in flight per group.
// rec stores are NON-TEMPORAL: no write-allocate RFO, no L2 pollution.
__global__ __launch_bounds__(256) void score_scatter_packed(
    const unsigned short* __restrict__ fph,
    const int* __restrict__ src0, const int* __restrict__ dst0,
    const int* __restrict__ src1, const int* __restrict__ dst1,
    const int* __restrict__ src2, const int* __restrict__ dst2,
    int* __restrict__ cursor, uint2* __restrict__ rec, int n, int eg)
{
    long tid = (long)blockIdx.x*blockDim.x + threadIdx.x;
    long gid = tid >> 3;
    long tot = 3L*eg;
    long e0 = gid*4;
    if(e0 >= tot) return;
    int l = threadIdx.x & 7;
    const uint4* f4 = (const uint4*)fph;

    int sv[4], dv[4], gv[4];
    bool ok[4];
    #pragma unroll
    for(int q = 0; q < 4; q++){
        long e = e0 + q;
        ok[q] = (e < tot);
        long ee = ok[q] ? e : (tot - 1);
        int g = (int)(ee / eg);
        int i = (int)(ee - (long)g*eg);
        const int* sp = g==0 ? src0 : (g==1 ? src1 : src2);
        const int* dp = g==0 ? dst0 : (g==1 ? dst1 : dst2);
        sv[q] = __builtin_nontemporal_load(sp + i);
        dv[q] = __builtin_nontemporal_load(dp + i);
        gv[q] = g;
    }
    uint4 A[4], B[4];
    #pragma unroll
    for(int q = 0; q < 4; q++){
        A[q] = f4[(long)sv[q]*8 + l];
        B[q] = f4[(long)dv[q]*8 + l];
    }
    float p[4];
    #pragma unroll
    for(int q = 0; q < 4; q++){
        float v;
        v  = bl(A[q].x)*bl(B[q].x) + bh(A[q].x)*bh(B[q].x);
        v += bl(A[q].y)*bl(B[q].y) + bh(A[q].y)*bh(B[q].y);
        v += bl(A[q].z)*bl(B[q].z) + bh(A[q].z)*bh(B[q].z);
        v += bl(A[q].w)*bl(B[q].w) + bh(A[q].w)*bh(B[q].w);
        p[q] = v;
    }
    #pragma unroll
    for(int q = 0; q < 4; q++){
        p[q] += __shfl_xor(p[q], 1);
        p[q] += __shfl_xor(p[q], 2);
        p[q] += __shfl_xor(p[q], 4);
    }
    if(l == 0){
        int pos[4];
        #pragma unroll
        for(int q = 0; q < 4; q++){
            if(ok[q]) pos[q] = atomicAdd(&cursor[(long)gv[q]*n + dv[q]], 1);
        }
        #pragma unroll
        for(int q = 0; q < 4; q++){
            if(ok[q]) ntstore_u2(&rec[pos[q]], (unsigned)sv[q],
                                 __float_as_uint(p[q]*0.125f));  // /sqrt(64)
        }
    }
}

// ====== per-row softmax, online 2-sweep: rec[].y := exp(s-m)/den ======
__global__ __launch_bounds__(256) void row_softmax_kernel(const int* __restrict__ rowptr,
                                                          uint2* __restrict__ rec, int n3)
{
    int i = blockIdx.x*blockDim.x + threadIdx.x;
    if(i >= n3) return;
    int beg = rowptr[i], end = rowptr[i+1];
    if(beg == end) return;
    float m = -1e30f, den = 0.f;
    for(int j = beg; j < end; j++){
        float s = __uint_as_float(rec[j].y);
        float nm = fmaxf(m, s);
        den = den*__expf(m - nm) + __expf(s - nm);
        m = nm;
    }
    float inv = 1.0f/(den + 1e-16f);
    for(int j = beg; j < end; j++)
        rec[j].y = __float_as_uint(__expf(__uint_as_float(rec[j].y) - m)*inv);
}

// ====== propagate (CSR record gather, blend fused).
//  L1 + uniform label_init: zero-gather shortcut. Rec reads NON-TEMPORAL
//  (streaming) so h stays L2-resident. ======
template<int L1>
__global__ __launch_bounds__(256) void propagate_rec_kernel(
    const int* __restrict__ rowptr, const uint2* __restrict__ rec,
    const float* __restrict__ h_in_f32, const unsigned short* __restrict__ h_in_bf,
    unsigned short* __restrict__ h_next, const float* __restrict__ labels,
    const void* __restrict__ maskp, const unsigned* __restrict__ flags, int n)
{
    long tid = (long)blockIdx.x*blockDim.x + threadIdx.x;
    int row = (int)(tid >> 4);
    int c = (int)(tid & 15);
    if(row >= 3*n) return;
    int g = row / n;
    int d = row - g*n;
    int beg = rowptr[row], end = rowptr[row+1];
    unsigned fl = *flags;
    float acc = 0.f;
    if(L1){
        if(!(fl & 4u)){
            acc = (end > beg) ? h_in_f32[0] : 0.f;   // uniform label_init shortcut
        } else {
            for(int j = beg; j < end; j++){
                uint2 r = ntload_u2(&rec[j]);
                acc += __uint_as_float(r.y) * h_in_f32[(long)r.x*16 + c];
            }
        }
    } else {
        const unsigned short* hg = h_in_bf + (long)g*n*16;
        int j = beg;
        for(; j + 1 < end; j += 2){
            uint2 r0 = ntload_u2(&rec[j]);
            uint2 r1 = ntload_u2(&rec[j+1]);
            acc += __uint_as_float(r0.y)*b2f(hg[(long)r0.x*16 + c])
                 + __uint_as_float(r1.y)*b2f(hg[(long)r1.x*16 + c]);
        }
        if(j < end){
            uint2 r0 = ntload_u2(&rec[j]);
            acc += __uint_as_float(r0.y)*b2f(hg[(long)r0.x*16 + c]);
        }
    }
    float mk = get_mask(maskp, fl, d);
    float val = acc*(1.0f - mk) + labels[(long)d*16 + c]*mk;
    h_next[(long)row*16 + c] = f2bf(val);
}

// ================= NS aggregate + attention mix + gate, fully fused =================
__global__ __launch_bounds__(256) void ns_final_kernel(
    const unsigned short* __restrict__ hf, const float* __restrict__ h0c,
    const unsigned short* __restrict__ h1c, const int* __restrict__ nei,
    const float* __restrict__ attn, const float* __restrict__ alpha,
    float* __restrict__ out, int n, int kk)
{
    long tid = (long)blockIdx.x*blockDim.x + threadIdx.x;
    int node = (int)(tid >> 4);
    int c = (int)(tid & 15);
    if(node >= n) return;
    const int* nrow = nei + (long)node*kk;
    float acc = 0.f;
    for(int j = 0; j < kk; j++){
        int nb = __builtin_nontemporal_load(nrow + j);
        acc += b2f(h1c[(long)nb*16 + c]);
    }
    float ns = h0c[(long)node*16 + c] + acc*(1.0f/(float)kk);
    float a0 = attn[node*3], a1 = attn[node*3+1], a2 = attn[node*3+2];
    float mx = fmaxf(a0, fmaxf(a1, a2));
    float e0 = __expf(a0-mx), e1 = __expf(a1-mx), e2 = __expf(a2-mx);
    float inv = 1.0f/(e0+e1+e2);
    long gs = (long)n*16;
    long idx = (long)node*16 + c;
    float lp = (e0*b2f(__builtin_nontemporal_load(hf + idx))
              + e1*b2f(__builtin_nontemporal_load(hf + gs + idx))
              + e2*b2f(__builtin_nontemporal_load(hf + 2*gs + idx)))*inv;
    float al = alpha[node];
    float sg = 1.0f/(1.0f + __expf(-al));
    out[idx]        = sg*lp + (1.0f - sg)*ns;
    out[gs + idx]   = lp;
    out[2*gs + idx] = ns;
}

// ================= launch =================
extern "C" void kernel_launch(void* const* d_in, const int* in_sizes, int n_in,
                              void* d_out, int out_size, void* d_ws, size_t ws_size,
                              hipStream_t stream)
{
    const float* feats0     = (const float*)d_in[0];
    const float* feats1     = (const float*)d_in[1];
    const float* W0         = (const float*)d_in[2];
    const float* b0         = (const float*)d_in[3];
    const float* W1         = (const float*)d_in[4];
    const float* b1         = (const float*)d_in[5];
    const float* Wp         = (const float*)d_in[6];
    const float* Wcls       = (const float*)d_in[7];
    const float* bcls       = (const float*)d_in[8];
    const float* alpha      = (const float*)d_in[9];
    const float* attn       = (const float*)d_in[10];
    const float* labels     = (const float*)d_in[11];
    const float* label_init = (const float*)d_in[12];
    const void*  maskp      = d_in[13];
    const int*   nei        = (const int*)d_in[14];
    const int*   src0       = (const int*)d_in[15];
    const int*   dst0       = (const int*)d_in[16];
    const int*   src1       = (const int*)d_in[17];
    const int*   dst1       = (const int*)d_in[18];
    const int*   src2       = (const int*)d_in[19];
    const int*   dst2       = (const int*)d_in[20];

    const int n  = in_sizes[9];          // N
    const int n1 = in_sizes[1] / 128;    // N1
    const int eg = in_sizes[15];         // E per graph
    const int kk = in_sizes[14] / n;     // K
    const int n3 = 3*n;

    // ---- workspace arena (~70 MB) ----
    char* ws = (char*)d_ws;
    size_t off = 0;
    auto alloc = [&](size_t bytes)->char*{
        char* p = ws + off; off += (bytes + 255) & ~(size_t)255; return p;
    };
    unsigned*       flags  = (unsigned*)      alloc(256);
    unsigned short* fph    = (unsigned short*)alloc((size_t)n*64*2);      // 12.8 MB
    float*          h0c    = (float*)         alloc((size_t)n*16*4);      // 6.4 MB
    unsigned short* h1c    = (unsigned short*)alloc((size_t)n1*16*2);     // 2.56 MB
    float*          W0c    = (float*)         alloc(2048*4);
    float*          W1c    = (float*)         alloc(2048*4);
    float*          b0c    = (float*)         alloc(64);
    float*          b1c    = (float*)         alloc(64);
    int*            deg    = (int*)           alloc((size_t)n3*4);        // aliases incl
    int*            cursor = (int*)           alloc((size_t)n3*4);
    int*            bsum   = (int*)           alloc(512*4);
    int*            rowptr = (int*)           alloc(((size_t)n3+1)*4);
    uint2*          rec    = (uint2*)         alloc((size_t)3*eg*8);      // 24 MB
    unsigned short* hA     = (unsigned short*)alloc((size_t)n3*16*2);     // 9.6 MB
    unsigned short* hB     = (unsigned short*)alloc((size_t)n3*16*2);     // 9.6 MB
    int* incl = deg;  // safe alias: scanA reads deg[i] before writing incl[i], per-thread

    // 1. init + combined detection (mask dtype + label_init uniformity)
    hipMemsetAsync(flags, 0, 4, stream);
    hipMemsetAsync(deg, 0, (size_t)n3*4, stream);
    {
        long li_n = (long)n*16;
        detect_kernel<<<(unsigned)((li_n+255)/256), 256, 0, stream>>>(
            (const unsigned char*)maskp, n, (const unsigned*)label_init, li_n, flags);
    }

    // 2. tiny weight products
    small_w_kernel<<<1, 256, 0, stream>>>(W0, b0, W1, b1, Wcls, bcls, W0c, W1c, b0c, b1c);

    // 3. projections
    proj_fused0<<<(n+31)/32, 256, 0, stream>>>(feats0, Wp, W0c, b0c, fph, h0c, n);
    proj16_kernel<<<(n1+63)/64, 256, 0, stream>>>(feats1, W1c, b1c, h1c, n1);

    // 4. CSR rowptr build
    {
        long tot = 3L*eg;
        count_kernel<<<(unsigned)((tot+255)/256), 256, 0, stream>>>(dst0, dst1, dst2, deg, n, eg);
    }
    int nb = (n3 + 1023)/1024;
    scanA_kernel<<<nb, 256, 0, stream>>>(deg, incl, bsum, n3);
    scanB_kernel<<<1, 512, 0, stream>>>(bsum, nb);
    scanC_kernel<<<(n3+255)/256, 256, 0, stream>>>(incl, bsum, rowptr, cursor, n3);

    // 5. FUSED scores + packed-record scatter (4-edge ILP, NT stores)
    {
        long groups = (3L*eg + 3)/4;
        long tthreads = groups*8;
        score_scatter_packed<<<(unsigned)((tthreads+255)/256), 256, 0, stream>>>(
            fph, src0,dst0,src1,dst1,src2,dst2, cursor, rec, n, eg);
    }
    // 6. per-row online softmax normalize (in-place; shared by all 3 layers)
    row_softmax_kernel<<<(n3+255)/256, 256, 0, stream>>>(rowptr, rec, n3);

    // 7. LP layers: layer 1 uniform-shortcut; layers 2,3 bf16 h gathers.
    {
        long tot = (long)n3*16;
        unsigned gsz = (unsigned)((tot+255)/256);
        propagate_rec_kernel<1><<<gsz, 256, 0, stream>>>(
            rowptr, rec, label_init, nullptr, hA, labels, maskp, flags, n);
        propagate_rec_kernel<0><<<gsz, 256, 0, stream>>>(
            rowptr, rec, nullptr, hA, hB, labels, maskp, flags, n);
        propagate_rec_kernel<0><<<gsz, 256, 0, stream>>>(
            rowptr, rec, nullptr, hB, hA, labels, maskp, flags, n);
    }
    // final h in hA

    // 8. NS aggregate + final mix
    ns_final_kernel<<<(unsigned)(((long)n*16+255)/256), 256, 0, stream>>>(
        hA, h0c, h1c, nei, attn, alpha, (float*)d_out, n, kk);
}